// Round 5
// baseline (2203.445 us; speedup 1.0000x reference)
//
#include <hip/hip_runtime.h>
#include <hip/hip_fp16.h>

#define NSTATES 256
#define SEQ 1024
#define NSYM 100

// ---------- prep: W[a][i][j] f32 -> WB[a][w][j][i'] fp16 (13 MB, once) ----------
// WB[(((a*16 + w)*256) + j)*16 + i'] = W[a][16w + i'][j]
// i.e. per (symbol, wave) a contiguous 256x16 fp16 panel: output block's W^T.
__global__ __launch_bounds__(256) void prep_b(const float* __restrict__ W,
                                              __half* __restrict__ WB) {
    __shared__ float tile[16][256];
    int a = blockIdx.y;
    int w = blockIdx.x;
    int t = threadIdx.x;
    const float* src = W + ((size_t)a * 256 + w * 16) * 256;
#pragma unroll
    for (int r = 0; r < 16; r++) tile[r][t] = src[r * 256 + t];
    __syncthreads();
    __half tmp[16];
#pragma unroll
    for (int i = 0; i < 16; i++) tmp[i] = __float2half(tile[i][t]);
    ushort4* dst = (ushort4*)(WB + ((((size_t)a * 16 + w) * 256) + t) * 16);
    const ushort4* s = (const ushort4*)tmp;
#pragma unroll
    for (int q = 0; q < 4; q++) dst[q] = s[q];
}

// ---------- main chain kernel: output-partitioned, ONE barrier per step ----------
// grid = B, block = 1024 (16 waves). Wave w owns outputs i in [16w,16w+16).
// Lane l accumulates i' = (l&3)*4..+3 over j = k*16 + (l>>2), k=0..15; a 4-level
// shfl_xor butterfly (masks 4,8,16,32) completes the dot products in-register.
// Lanes 0..3 write float4 to the ping-pong h buffer; single __syncthreads per step.
// W loads for step t+1 are register-prefetched before step t's compute.
__global__ __launch_bounds__(1024) void pann_fwd_b(const int* __restrict__ xs,
                                                   const int* __restrict__ lengths,
                                                   const __half* __restrict__ WB,
                                                   const float* __restrict__ lin_w,
                                                   const float* __restrict__ lin_b,
                                                   float* __restrict__ out) {
    __shared__ float h[2][NSTATES];
    __shared__ float opart[2][NSTATES];
    __shared__ int xrow[SEQ];

    int b = blockIdx.x;
    int tid = threadIdx.x;
    int w = tid >> 6;
    int lane = tid & 63;

    xrow[tid] = xs[(size_t)b * SEQ + tid];
    if (tid < NSTATES) h[0][tid] = (tid == 0) ? 1.0f : 0.0f;
    int len = lengths[b];
    __syncthreads();

    // ushort4 view: per symbol 16384 ushort4; per wave panel 1024 ushort4.
    const ushort4* Wb4 = (const ushort4*)WB;
    const ushort4* wl = Wb4 + w * 1024 + lane;
    int hidx = lane >> 2;           // j offset within each k-group

    ushort4 Ra[16], Rb[16];
    {
        int x0 = __builtin_amdgcn_readfirstlane(xrow[0]);
        const ushort4* p = wl + (size_t)x0 * 16384;
#pragma unroll
        for (int k = 0; k < 16; k++) Ra[k] = p[k * 64];
    }

    int cur = 0;
    int t = 0;
#define PHASE(RC, RN)                                                         \
    {                                                                         \
        int tn = t + 1; if (tn >= len) tn = t;                                \
        int xn = __builtin_amdgcn_readfirstlane(xrow[tn]);                    \
        const ushort4* pn = wl + (size_t)xn * 16384;                          \
        _Pragma("unroll")                                                     \
        for (int k = 0; k < 16; k++) RN[k] = pn[k * 64];                      \
        float a0 = 0.f, a1 = 0.f, a2 = 0.f, a3 = 0.f;                         \
        _Pragma("unroll")                                                     \
        for (int k = 0; k < 16; k++) {                                        \
            float hj = h[cur][k * 16 + hidx];                                 \
            float2 f0 = __half22float2(*(const __half2*)&RC[k].x);            \
            float2 f1 = __half22float2(*(const __half2*)&RC[k].z);            \
            a0 = fmaf(f0.x, hj, a0);                                          \
            a1 = fmaf(f0.y, hj, a1);                                          \
            a2 = fmaf(f1.x, hj, a2);                                          \
            a3 = fmaf(f1.y, hj, a3);                                          \
        }                                                                     \
        _Pragma("unroll")                                                     \
        for (int m = 4; m <= 32; m <<= 1) {                                   \
            a0 += __shfl_xor(a0, m, 64);                                      \
            a1 += __shfl_xor(a1, m, 64);                                      \
            a2 += __shfl_xor(a2, m, 64);                                      \
            a3 += __shfl_xor(a3, m, 64);                                      \
        }                                                                     \
        if (lane < 4)                                                         \
            *(float4*)&h[cur ^ 1][w * 16 + lane * 4] =                        \
                make_float4(a0, a1, a2, a3);                                  \
        __syncthreads();                                                      \
        cur ^= 1;                                                             \
        t++;                                                                  \
    }

    while (t < len) {
        PHASE(Ra, Rb);
        if (t >= len) break;
        PHASE(Rb, Ra);
    }
#undef PHASE

    // ---- head: out[b,k] = lin_w[k,:] @ h + lin_b[k] ----
    if (tid < NSTATES) {
        float hv = h[cur][tid];
        opart[0][tid] = hv * lin_w[tid];
        opart[1][tid] = hv * lin_w[NSTATES + tid];
    }
    __syncthreads();
    for (int s = 128; s > 0; s >>= 1) {
        if (tid < s) {
            opart[0][tid] += opart[0][tid + s];
            opart[1][tid] += opart[1][tid + s];
        }
        __syncthreads();
    }
    if (tid == 0) {
        out[b * 2 + 0] = opart[0][0] + lin_b[0];
        out[b * 2 + 1] = opart[1][0] + lin_b[1];
    }
}

// ---------- fallback: f32 no-transpose path (only if d_ws too small) ----------
__global__ __launch_bounds__(1024) void pann_fwd_nt(const int* __restrict__ xs,
                                                    const int* __restrict__ lengths,
                                                    const float* __restrict__ W,
                                                    const float* __restrict__ lin_w,
                                                    const float* __restrict__ lin_b,
                                                    float* __restrict__ out) {
    __shared__ float hbuf[2][NSTATES];
    __shared__ float opart[2][NSTATES];
    __shared__ int xrow[SEQ];

    int b = blockIdx.x;
    int tid = threadIdx.x;
    int w = tid >> 6;
    int lane = tid & 63;

    xrow[tid] = xs[(size_t)b * SEQ + tid];
    if (tid < NSTATES) hbuf[0][tid] = (tid == 0) ? 1.0f : 0.0f;
    int len = lengths[b];
    __syncthreads();

    int cur = 0;
    for (int t = 0; t < len; t++) {
        int x = xrow[t];
        const float4* wp = (const float4*)(W + (size_t)x * (NSTATES * NSTATES));
        float4 hv = *(const float4*)&hbuf[cur][lane << 2];
#pragma unroll
        for (int ii = 0; ii < 4; ii++) {
            int i = (w << 4) + ii * 4;
#pragma unroll
            for (int k = 0; k < 4; k++) {
                int row = i + k;
                float4 wv = wp[row * 64 + lane];
                float p = wv.x * hv.x + wv.y * hv.y + wv.z * hv.z + wv.w * hv.w;
#pragma unroll
                for (int off = 32; off > 0; off >>= 1) p += __shfl_down(p, off);
                if (lane == 0) hbuf[cur ^ 1][row] = p;
            }
        }
        __syncthreads();
        cur ^= 1;
    }

    if (tid < NSTATES) {
        float hv = hbuf[cur][tid];
        opart[0][tid] = hv * lin_w[tid];
        opart[1][tid] = hv * lin_w[NSTATES + tid];
    }
    __syncthreads();
    for (int s = 128; s > 0; s >>= 1) {
        if (tid < s) {
            opart[0][tid] += opart[0][tid + s];
            opart[1][tid] += opart[1][tid + s];
        }
        __syncthreads();
    }
    if (tid == 0) {
        out[b * 2 + 0] = opart[0][0] + lin_b[0];
        out[b * 2 + 1] = opart[1][0] + lin_b[1];
    }
}

extern "C" void kernel_launch(void* const* d_in, const int* in_sizes, int n_in,
                              void* d_out, int out_size, void* d_ws, size_t ws_size,
                              hipStream_t stream) {
    const int* xs = (const int*)d_in[0];
    const int* lengths = (const int*)d_in[1];
    const float* W = (const float*)d_in[2];
    const float* lin_w = (const float*)d_in[3];
    const float* lin_b = (const float*)d_in[4];
    float* out = (float*)d_out;

    int B = in_sizes[0] / SEQ;
    size_t wbytes = (size_t)NSYM * NSTATES * NSTATES * sizeof(__half);

    if (ws_size >= wbytes) {
        __half* WB = (__half*)d_ws;
        dim3 tg(16, NSYM);
        prep_b<<<tg, 256, 0, stream>>>(W, WB);
        pann_fwd_b<<<B, 1024, 0, stream>>>(xs, lengths, WB, lin_w, lin_b, out);
    } else {
        pann_fwd_nt<<<B, 1024, 0, stream>>>(xs, lengths, W, lin_w, lin_b, out);
    }
}